// Round 1
// baseline (137.933 us; speedup 1.0000x reference)
//
#include <hip/hip_runtime.h>

#define NPOS 8192
#define NCH  8
#define CHUNK (NPOS / NCH)   // 1024

// workspace layout (float offsets)
#define OFF_XET   0u           // 8192*4  Xe^T  (column-major: float4 per column)
#define OFF_SET   32768u       // 8192*4  Se^T
#define OFF_NX    65536u       // 8192    |xe_j|^2
#define OFF_NS    73728u       // 8192    |se_j|^2
#define OFF_R     81920u       // 2       Rx, Rs (max norms)
#define OFF_PART  90112u       // 2*NCH*5*8192 = 655360 attention partials
#define OFF_XA    745472u      // 8192*4  Xa (row-major (4,8192) == flat of (8192,4))
#define OFF_SA    778240u      // 8192*4  Sa
#define OFF_MX2   811008u      // 8192*4  W2x @ Xa2  (flat (8192,4) == flat (4,8192))
#define OFF_MS2   843776u      // 8192*4  W2x @ Sa2

// ---------------------------------------------------------------- k1: Xe/Se
__global__ __launch_bounds__(256) void k_prep(
    const float* __restrict__ X, const float* __restrict__ S,
    const float* __restrict__ W1x, const float* __restrict__ W1s,
    float* __restrict__ ws)
{
    int n = blockIdx.x * 256 + threadIdx.x;
    if (n >= NPOS) return;
    float s4[4], x4[4];
#pragma unroll
    for (int k = 0; k < 4; ++k) { s4[k] = S[k * NPOS + n]; x4[k] = X[k * NPOS + n]; }
    float xe[4], se[4];
#pragma unroll
    for (int l = 0; l < 4; ++l) {
        float a = 0.f, b = 0.f;
#pragma unroll
        for (int k = 0; k < 4; ++k) {
            a = fmaf(W1x[l * 4 + k], s4[k], a);
            b = fmaf(W1s[l * 4 + k], x4[k], b);
        }
        xe[l] = a; se[l] = b;
    }
    ((float4*)(ws + OFF_XET))[n] = make_float4(xe[0], xe[1], xe[2], xe[3]);
    ((float4*)(ws + OFF_SET))[n] = make_float4(se[0], se[1], se[2], se[3]);
    ws[OFF_NX + n] = xe[0]*xe[0] + xe[1]*xe[1] + xe[2]*xe[2] + xe[3]*xe[3];
    ws[OFF_NS + n] = se[0]*se[0] + se[1]*se[1] + se[2]*se[2] + se[3]*se[3];
}

// ---------------------------------------------------------------- k2: R = max norm
__global__ __launch_bounds__(256) void k_rmax(float* __restrict__ ws)
{
    __shared__ float smx[256], sms[256];
    int tid = threadIdx.x;
    const float4* nx4 = (const float4*)(ws + OFF_NX);
    const float4* ns4 = (const float4*)(ws + OFF_NS);
    float mx = 0.f, ms = 0.f;
    for (int i = tid; i < NPOS / 4; i += 256) {
        float4 a = nx4[i], b = ns4[i];
        mx = fmaxf(mx, fmaxf(fmaxf(a.x, a.y), fmaxf(a.z, a.w)));
        ms = fmaxf(ms, fmaxf(fmaxf(b.x, b.y), fmaxf(b.z, b.w)));
    }
    smx[tid] = mx; sms[tid] = ms;
    __syncthreads();
    for (int s = 128; s; s >>= 1) {
        if (tid < s) {
            smx[tid] = fmaxf(smx[tid], smx[tid + s]);
            sms[tid] = fmaxf(sms[tid], sms[tid + s]);
        }
        __syncthreads();
    }
    if (tid == 0) { ws[OFF_R] = sqrtf(smx[0]); ws[OFF_R + 1] = sqrtf(sms[0]); }
}

// ---------------------------------------------------------------- k3: attention partials
// block = 256 columns j; blockIdx.y = i-chunk; blockIdx.z = branch
__global__ __launch_bounds__(256) void k_attn(float* __restrict__ ws)
{
    int branch = blockIdx.z;
    const float4* vT = (const float4*)(ws + (branch ? OFF_SET : OFF_XET));
    const float*  nn = ws + (branch ? OFF_NS : OFF_NX);
    float Rv = ws[OFF_R + branch];

    int j = blockIdx.x * 256 + threadIdx.x;
    float4 xj = vT[j];
    float Mj = Rv * sqrtf(nn[j]);   // >= max_i (xe_i . xe_j)  (Cauchy-Schwarz)

    __shared__ float4 tile[CHUNK];
    int i0 = blockIdx.y * CHUNK;
    for (int t = threadIdx.x; t < CHUNK; t += 256) tile[t] = vT[i0 + t];
    __syncthreads();

    float den = 0.f, n0 = 0.f, n1 = 0.f, n2 = 0.f, n3 = 0.f;
#pragma unroll 4
    for (int i = 0; i < CHUNK; ++i) {
        float4 xi = tile[i];
        float s = fmaf(xj.x, xi.x, fmaf(xj.y, xi.y, fmaf(xj.z, xi.z, xj.w * xi.w)));
        float p = __expf(s - Mj);
        den += p;
        n0 = fmaf(p, xi.x, n0);
        n1 = fmaf(p, xi.y, n1);
        n2 = fmaf(p, xi.z, n2);
        n3 = fmaf(p, xi.w, n3);
    }
    float* part = ws + OFF_PART + (size_t)(branch * NCH + blockIdx.y) * 5 * NPOS;
    part[0 * NPOS + j] = n0;
    part[1 * NPOS + j] = n1;
    part[2 * NPOS + j] = n2;
    part[3 * NPOS + j] = n3;
    part[4 * NPOS + j] = den;
}

// ---------------------------------------------------------------- k4: finalize Xa/Sa
__global__ __launch_bounds__(256) void k_fin(float* __restrict__ ws)
{
    int branch = blockIdx.y;
    int j = blockIdx.x * 256 + threadIdx.x;
    float num[4] = {0.f, 0.f, 0.f, 0.f}, den = 0.f;
#pragma unroll
    for (int c = 0; c < NCH; ++c) {
        const float* part = ws + OFF_PART + (size_t)(branch * NCH + c) * 5 * NPOS;
        num[0] += part[0 * NPOS + j];
        num[1] += part[1 * NPOS + j];
        num[2] += part[2 * NPOS + j];
        num[3] += part[3 * NPOS + j];
        den    += part[4 * NPOS + j];
    }
    float inv = 1.0f / den;
    float* out = ws + (branch ? OFF_SA : OFF_XA);
#pragma unroll
    for (int l = 0; l < 4; ++l) out[l * NPOS + j] = num[l] * inv;
}

// ---------------------------------------------------------------- k5: M = W2x @ [Xa2|Sa2]
// block: 8 rows of W2x; thread strides k in float4 units; 64 accumulators.
#define ACC4(r, wv, q0, q1, q2, q3, comp, cc)                 \
    acc[r][cc] = fmaf(wv.x, q0.comp, acc[r][cc]);             \
    acc[r][cc] = fmaf(wv.y, q1.comp, acc[r][cc]);             \
    acc[r][cc] = fmaf(wv.z, q2.comp, acc[r][cc]);             \
    acc[r][cc] = fmaf(wv.w, q3.comp, acc[r][cc]);

__global__ __launch_bounds__(256) void k_gemv(
    const float* __restrict__ W2, float* __restrict__ ws)
{
    const float* xa = ws + OFF_XA;
    const float* sa = ws + OFF_SA;
    int r0 = blockIdx.x * 8;
    int tid = threadIdx.x;

    float acc[8][8];
#pragma unroll
    for (int r = 0; r < 8; ++r)
#pragma unroll
        for (int c = 0; c < 8; ++c) acc[r][c] = 0.f;

    for (int it = 0; it < 8; ++it) {
        int k4 = it * 256 + tid;                 // float4 index along k (0..2047)
        const float4* xp = (const float4*)(xa + (size_t)k4 * 16);
        const float4* sp = (const float4*)(sa + (size_t)k4 * 16);
        float4 a0 = xp[0], a1 = xp[1], a2 = xp[2], a3 = xp[3];
        float4 b0 = sp[0], b1 = sp[1], b2 = sp[2], b3 = sp[3];
#pragma unroll
        for (int r = 0; r < 8; ++r) {
            float4 wv = *(const float4*)(W2 + (size_t)(r0 + r) * NPOS + (size_t)k4 * 4);
            ACC4(r, wv, a0, a1, a2, a3, x, 0)
            ACC4(r, wv, a0, a1, a2, a3, y, 1)
            ACC4(r, wv, a0, a1, a2, a3, z, 2)
            ACC4(r, wv, a0, a1, a2, a3, w, 3)
            ACC4(r, wv, b0, b1, b2, b3, x, 4)
            ACC4(r, wv, b0, b1, b2, b3, y, 5)
            ACC4(r, wv, b0, b1, b2, b3, z, 6)
            ACC4(r, wv, b0, b1, b2, b3, w, 7)
        }
    }

    // reduce 64 accumulators across 256 threads
    __shared__ float sred[4 * 64];
    int wave = tid >> 6, lane = tid & 63;
#pragma unroll
    for (int r = 0; r < 8; ++r)
#pragma unroll
        for (int c = 0; c < 8; ++c) {
            float v = acc[r][c];
            for (int off = 32; off; off >>= 1) v += __shfl_down(v, off);
            if (lane == 0) sred[wave * 64 + r * 8 + c] = v;
        }
    __syncthreads();
    if (tid < 64) {
        float v = sred[tid] + sred[64 + tid] + sred[128 + tid] + sred[192 + tid];
        int r = tid >> 3, c = tid & 7;
        float* dst = ws + ((c < 4) ? OFF_MX2 : OFF_MS2);
        dst[(size_t)(r0 + r) * 4 + (c & 3)] = v;
    }
}

// ---------------------------------------------------------------- k6: epilogue + 3x1 conv
// blockIdx.x = k-tile (256), blockIdx.y = branch (0: X_hat, 1: S_hat)
__global__ __launch_bounds__(256) void k_conv(
    const float* __restrict__ X, const float* __restrict__ S,
    const float* __restrict__ cwx, const float* __restrict__ cbx,
    const float* __restrict__ cws, const float* __restrict__ cbs,
    const float* __restrict__ ws, float* __restrict__ out)
{
    int branch = blockIdx.y;
    int k0 = blockIdx.x * 256;
    const float* M2 = ws + (branch ? OFF_MS2 : OFF_MX2);
    const float* cw = branch ? cws : cwx;
    const float* cb = branch ? cbs : cbx;

    __shared__ float h[8][264];     // channels x (k0-1 .. k0+256)
    __shared__ float wg[192];       // w[co][ci][kh] (kw=1 only; W=1 image)
    __shared__ float bg[8];

    int tid = threadIdx.x;
    if (tid < 192) {
        int co = tid / 24, rem = tid % 24, ci = rem / 3, kh = rem % 3;
        wg[tid] = cw[co * 72 + ci * 9 + kh * 3 + 1];
    }
    if (tid < 8) bg[tid] = cb[tid];

    for (int idx = tid; idx < 8 * 258; idx += 256) {
        int ch = idx / 258, kk = idx % 258;
        int k = k0 - 1 + kk;
        float v = 0.f;
        if (k >= 0 && k < NPOS) {
            int l = ch & 3;
            if (branch == 0) {
                float xv = X[l * NPOS + k];
                v = (ch < 4) ? M2[l * NPOS + k] * xv : xv;
            } else {
                v = (ch < 4) ? M2[l * NPOS + k] * X[l * NPOS + k] : S[l * NPOS + k];
                v += sinf((float)k);      // sinusoid table with d_hid=B=1 -> sin(pos)
            }
        }
        h[ch][kk] = v;
    }
    __syncthreads();

    int k = k0 + tid;
    int kk = tid + 1;
#pragma unroll
    for (int co = 0; co < 8; ++co) {
        float a = bg[co];
#pragma unroll
        for (int ci = 0; ci < 8; ++ci) {
            a = fmaf(wg[co * 24 + ci * 3 + 0], h[ci][kk - 1], a);
            a = fmaf(wg[co * 24 + ci * 3 + 1], h[ci][kk    ], a);
            a = fmaf(wg[co * 24 + ci * 3 + 2], h[ci][kk + 1], a);
        }
        out[(size_t)(branch * 8 + co) * NPOS + k] = a;
    }
}

// ----------------------------------------------------------------
extern "C" void kernel_launch(void* const* d_in, const int* in_sizes, int n_in,
                              void* d_out, int out_size, void* d_ws, size_t ws_size,
                              hipStream_t stream)
{
    const float* X   = (const float*)d_in[0];
    const float* S   = (const float*)d_in[1];
    const float* W1x = (const float*)d_in[2];
    const float* W1s = (const float*)d_in[3];
    const float* W2  = (const float*)d_in[4];
    const float* cwx = (const float*)d_in[5];
    const float* cbx = (const float*)d_in[6];
    const float* cws = (const float*)d_in[7];
    const float* cbs = (const float*)d_in[8];
    float* out = (float*)d_out;
    float* ws  = (float*)d_ws;

    k_prep<<<dim3(NPOS / 256), 256, 0, stream>>>(X, S, W1x, W1s, ws);
    k_rmax<<<dim3(1), 256, 0, stream>>>(ws);
    k_attn<<<dim3(NPOS / 256, NCH, 2), 256, 0, stream>>>(ws);
    k_fin<<<dim3(NPOS / 256, 2), 256, 0, stream>>>(ws);
    k_gemv<<<dim3(NPOS / 8), 256, 0, stream>>>(W2, ws);
    k_conv<<<dim3(NPOS / 256, 2), 256, 0, stream>>>(X, S, cwx, cbx, cws, cbs, ws, out);
}